// Round 1
// baseline (2477.583 us; speedup 1.0000x reference)
//
#include <hip/hip_runtime.h>

#define NB 4
#define NPI 12000
#define NM 32
#define NPTS (NB*NPI*NM)      // 1536000
#define NPIL (NB*NPI)         // 48000
#define K1_BLOCKS 1500
#define K1_STRIDE (K1_BLOCKS*256)   // 384000
#define K1_ITERS 4                  // NPTS / K1_STRIDE

// ---------------------------------------------------------------- helpers

__device__ __forceinline__ float zcenter_of_group(float z) {
  // mean of z over the 32-lane group (one pillar)
  float s = z;
#pragma unroll
  for (int m = 1; m < 32; m <<= 1) s += __shfl_xor(s, m, 32);
  return s * (1.0f / 32.0f);
}

__device__ __forceinline__ void make_f(float4 v, int4 cc, int np, int m, float zc, float f[9]) {
  const float cx = ((float)cc.w + 0.5f) * 0.16f + 0.0f;
  const float cy = ((float)cc.z + 0.5f) * 0.16f - 39.68f;
  f[0] = v.x; f[1] = v.y; f[2] = v.z; f[3] = v.w;
  f[4] = v.x - cx; f[5] = v.y - cy; f[6] = cx; f[7] = cy; f[8] = zc;
  const float msk = (m < np) ? 1.0f : 0.0f;
#pragma unroll
  for (int i = 0; i < 9; ++i) f[i] *= msk;
}

// ------------------------------------------------- K1: f-moments (layer-1 stats)
// 54 values: Sf[9], Sff upper-triangular [45]. Block partials -> P1[v][block].

__global__ __launch_bounds__(256) void k_moments(
    const float4* __restrict__ vox, const int4* __restrict__ coords,
    const int* __restrict__ npnts, float* __restrict__ P1) {
  const int t = blockIdx.x * 256 + threadIdx.x;
  float acc[54];
#pragma unroll
  for (int v = 0; v < 54; ++v) acc[v] = 0.0f;

#pragma unroll
  for (int j = 0; j < K1_ITERS; ++j) {
    const int pt = t + j * K1_STRIDE;
    const int pil = pt >> 5;
    const int m = pt & 31;
    const float4 v = vox[pt];
    const int4 cc = coords[pil];
    const int np = npnts[pil];
    const float zc = zcenter_of_group(v.z);
    float f[9];
    make_f(v, cc, np, m, zc, f);
    int vi = 0;
#pragma unroll
    for (int i = 0; i < 9; ++i) acc[vi++] += f[i];
#pragma unroll
    for (int i = 0; i < 9; ++i)
#pragma unroll
      for (int jj = i; jj < 9; ++jj) acc[vi++] += f[i] * f[jj];
  }

  // wave butterfly each of the 54 values
#pragma unroll
  for (int v = 0; v < 54; ++v) {
    float x = acc[v];
#pragma unroll
    for (int s = 1; s < 64; s <<= 1) x += __shfl_xor(x, s, 64);
    acc[v] = x;
  }
  __shared__ float red[4][54];
  const int wave = threadIdx.x >> 6, lane = threadIdx.x & 63;
  if (lane == 0) {
#pragma unroll
    for (int v = 0; v < 54; ++v) red[wave][v] = acc[v];
  }
  __syncthreads();
  if (threadIdx.x < 54) {
    float s = red[0][threadIdx.x] + red[1][threadIdx.x] + red[2][threadIdx.x] + red[3][threadIdx.x];
    P1[threadIdx.x * K1_BLOCKS + blockIdx.x] = s;
  }
}

// ------------------------------------------------- generic row reduce (f32 -> f64)

__global__ __launch_bounds__(256) void k_rowreduce(
    const float* __restrict__ src, double* __restrict__ dst, int ncols) {
  const int row = blockIdx.x;
  const float* p = src + row * ncols;
  double sd = 0.0;
  for (int i = threadIdx.x; i < ncols; i += 256) sd += (double)p[i];
#pragma unroll
  for (int s = 1; s < 64; s <<= 1) sd += __shfl_xor(sd, s, 64);
  __shared__ double rd[4];
  const int wave = threadIdx.x >> 6, lane = threadIdx.x & 63;
  if (lane == 0) rd[wave] = sd;
  __syncthreads();
  if (threadIdx.x == 0) dst[row] = rd[0] + rd[1] + rd[2] + rd[3];
}

// ------------------------------------------------- finalize layer-1 BN params

__global__ void k_fin1(const double* __restrict__ T1, const float* __restrict__ W1,
                       const float* __restrict__ g1, const float* __restrict__ b1,
                       float* __restrict__ params) {
  const int c = threadIdx.x;  // 64
  double w[9];
#pragma unroll
  for (int i = 0; i < 9; ++i) w[i] = (double)W1[i * 64 + c];
  double mean = 0.0;
#pragma unroll
  for (int i = 0; i < 9; ++i) mean += w[i] * T1[i];
  mean /= (double)NPTS;
  double e2 = 0.0;
  int v = 9;
#pragma unroll
  for (int i = 0; i < 9; ++i)
#pragma unroll
    for (int j = i; j < 9; ++j) {
      const double t = T1[v++] * w[i] * w[j];
      e2 += (i == j) ? t : 2.0 * t;
    }
  e2 /= (double)NPTS;
  const double var = e2 - mean * mean;
  const double a = (double)g1[c] / sqrt(var + 0.001);
  params[c] = (float)a;
  params[64 + c] = (float)((double)b1[c] - mean * a);
}

// ------------------------------------------------- K3: layer-2 stats (sum/sumsq of y2)

__global__ __launch_bounds__(256) void k_stats2(
    const float4* __restrict__ vox, const int4* __restrict__ coords,
    const int* __restrict__ npnts, const float* __restrict__ W1,
    const float* __restrict__ W2, const float* __restrict__ params,
    float* __restrict__ P2) {
  __shared__ __align__(16) float W1t[64 * 12];   // [c][i] padded to 12
  __shared__ __align__(16) float W2t[64 * 64];   // [c][k]
  __shared__ float a1s[64], b1s[64];
  for (int i = threadIdx.x; i < 768; i += 256) {
    const int c = i / 12, k = i % 12;
    W1t[i] = (k < 9) ? W1[k * 64 + c] : 0.0f;
  }
  for (int i = threadIdx.x; i < 4096; i += 256) {
    const int c = i >> 6, k = i & 63;
    W2t[i] = W2[k * 64 + c];
  }
  if (threadIdx.x < 64) { a1s[threadIdx.x] = params[threadIdx.x]; b1s[threadIdx.x] = params[64 + threadIdx.x]; }
  __syncthreads();

  const int t = blockIdx.x * 256 + threadIdx.x;
  const int lane = threadIdx.x & 63;
  float psum = 0.0f, psq = 0.0f;  // for channel == lane

#pragma unroll 1
  for (int j = 0; j < K1_ITERS; ++j) {
    const int pt = t + j * K1_STRIDE;
    const int pil = pt >> 5;
    const int m = pt & 31;
    const float4 v = vox[pt];
    const int4 cc = coords[pil];
    const int np = npnts[pil];
    const float zc = zcenter_of_group(v.z);
    float f[9];
    make_f(v, cc, np, m, zc, f);

    float h1[64];
#pragma unroll
    for (int c = 0; c < 64; ++c) {
      float y = 0.0f;
#pragma unroll
      for (int i = 0; i < 9; ++i) y = fmaf(f[i], W1t[c * 12 + i], y);
      h1[c] = fmaxf(fmaf(y, a1s[c], b1s[c]), 0.0f);
    }

    for (int c = 0; c < 64; ++c) {
      float y2 = 0.0f;
#pragma unroll
      for (int k = 0; k < 64; ++k) y2 = fmaf(h1[k], W2t[c * 64 + k], y2);
      float s1 = y2, s2 = y2 * y2;
#pragma unroll
      for (int s = 1; s < 64; s <<= 1) {
        s1 += __shfl_xor(s1, s, 64);
        s2 += __shfl_xor(s2, s, 64);
      }
      if (lane == c) { psum += s1; psq += s2; }
    }
  }

  __shared__ float redS[4][64], redQ[4][64];
  const int wave = threadIdx.x >> 6;
  redS[wave][lane] = psum;
  redQ[wave][lane] = psq;
  __syncthreads();
  if (threadIdx.x < 64) {
    const int l = threadIdx.x;
    const float s = redS[0][l] + redS[1][l] + redS[2][l] + redS[3][l];
    const float q = redQ[0][l] + redQ[1][l] + redQ[2][l] + redQ[3][l];
    P2[l * K1_BLOCKS + blockIdx.x] = s;
    P2[(64 + l) * K1_BLOCKS + blockIdx.x] = q;
  }
}

// ------------------------------------------------- finalize layer-2 BN params

__global__ void k_fin2(const double* __restrict__ T2, const float* __restrict__ g2,
                       const float* __restrict__ b2, float* __restrict__ params) {
  const int c = threadIdx.x;  // 64
  const double mean = T2[c] / (double)NPTS;
  const double var = T2[64 + c] / (double)NPTS - mean * mean;
  const double a = (double)g2[c] / sqrt(var + 0.001);
  params[128 + c] = (float)a;
  params[192 + c] = (float)((double)b2[c] - mean * a);
}

// ------------------------------------------------- K5: output pass (h2, max over m)

__global__ __launch_bounds__(256) void k_out(
    const float4* __restrict__ vox, const int4* __restrict__ coords,
    const int* __restrict__ npnts, const float* __restrict__ W1,
    const float* __restrict__ W2, const float* __restrict__ params,
    float* __restrict__ out) {
  __shared__ __align__(16) float W1t[64 * 12];
  __shared__ __align__(16) float W2t[64 * 64];
  __shared__ float a1s[64], b1s[64], a2s[64], b2s[64];
  for (int i = threadIdx.x; i < 768; i += 256) {
    const int c = i / 12, k = i % 12;
    W1t[i] = (k < 9) ? W1[k * 64 + c] : 0.0f;
  }
  for (int i = threadIdx.x; i < 4096; i += 256) {
    const int c = i >> 6, k = i & 63;
    W2t[i] = W2[k * 64 + c];
  }
  if (threadIdx.x < 64) {
    a1s[threadIdx.x] = params[threadIdx.x];
    b1s[threadIdx.x] = params[64 + threadIdx.x];
    a2s[threadIdx.x] = params[128 + threadIdx.x];
    b2s[threadIdx.x] = params[192 + threadIdx.x];
  }
  __syncthreads();

  const int pt = blockIdx.x * 256 + threadIdx.x;
  const int pil = pt >> 5;
  const int m = pt & 31;
  const float4 v = vox[pt];
  const int4 cc = coords[pil];
  const int np = npnts[pil];
  const float zc = zcenter_of_group(v.z);
  float f[9];
  make_f(v, cc, np, m, zc, f);

  float h1[64];
#pragma unroll
  for (int c = 0; c < 64; ++c) {
    float y = 0.0f;
#pragma unroll
    for (int i = 0; i < 9; ++i) y = fmaf(f[i], W1t[c * 12 + i], y);
    h1[c] = fmaxf(fmaf(y, a1s[c], b1s[c]), 0.0f);
  }

  for (int c = 0; c < 64; ++c) {
    float y2 = 0.0f;
#pragma unroll
    for (int k = 0; k < 64; ++k) y2 = fmaf(h1[k], W2t[c * 64 + k], y2);
    float h2 = fmaxf(fmaf(y2, a2s[c], b2s[c]), 0.0f);
    // max over the 32-lane pillar group (masked lanes carry the BN-shifted
    // constant, exactly as in the reference)
#pragma unroll
    for (int s = 1; s < 32; s <<= 1) h2 = fmaxf(h2, __shfl_xor(h2, s, 32));
    if (m == 0) out[pil * 64 + c] = h2;
  }
}

// ---------------------------------------------------------------- launch

extern "C" void kernel_launch(void* const* d_in, const int* in_sizes, int n_in,
                              void* d_out, int out_size, void* d_ws, size_t ws_size,
                              hipStream_t stream) {
  const float4* vox = (const float4*)d_in[0];
  const int4* coords = (const int4*)d_in[1];
  const int* npnts = (const int*)d_in[2];
  const float* W1 = (const float*)d_in[3];
  const float* g1 = (const float*)d_in[4];
  const float* b1 = (const float*)d_in[5];
  const float* W2 = (const float*)d_in[6];
  const float* g2 = (const float*)d_in[7];
  const float* b2 = (const float*)d_in[8];
  float* out = (float*)d_out;

  char* w = (char*)d_ws;
  double* T1 = (double*)w;                        // 54 doubles
  double* T2 = (double*)(w + 512);                // 128 doubles
  float* P1 = (float*)(w + 1536);                 // 54 * 1500 f32
  float* P2 = (float*)(w + 1536 + 54 * K1_BLOCKS * 4);        // 128 * 1500 f32
  float* params = (float*)(w + 1536 + (54 + 128) * K1_BLOCKS * 4);  // 256 f32

  k_moments<<<K1_BLOCKS, 256, 0, stream>>>(vox, coords, npnts, P1);
  k_rowreduce<<<54, 256, 0, stream>>>(P1, T1, K1_BLOCKS);
  k_fin1<<<1, 64, 0, stream>>>(T1, W1, g1, b1, params);
  k_stats2<<<K1_BLOCKS, 256, 0, stream>>>(vox, coords, npnts, W1, W2, params, P2);
  k_rowreduce<<<128, 256, 0, stream>>>(P2, T2, K1_BLOCKS);
  k_fin2<<<1, 64, 0, stream>>>(T2, g2, b2, params);
  k_out<<<6000, 256, 0, stream>>>(vox, coords, npnts, W1, W2, params, out);
}

// Round 2
// 2056.490 us; speedup vs baseline: 1.2048x; 1.2048x over previous
//
#include <hip/hip_runtime.h>
#include <math.h>

#define NB 4
#define NPI 12000
#define NM 32
#define NPTS (NB*NPI*NM)      // 1536000
#define NPIL (NB*NPI)         // 48000

// k_moments config
#define K1_BLOCKS 1500
#define K1_STRIDE (K1_BLOCKS*256)   // 384000
#define K1_ITERS 4                  // NPTS / K1_STRIDE

// heavy-kernel config: 128 points (4 pillars) per batch
#define CHUNK 128
#define NBATCH (NPTS/CHUNK)   // 12000
#define SB 1024               // grid for k_stats2 / k_out
#define LDH 68                // padded h1 row stride (floats); 68*4B=272B, 16B-aligned rows

// ---------------------------------------------------------------- helpers

__device__ __forceinline__ void make_f(float4 v, int4 cc, int np, int m, float zc, float f[9]) {
  const float cx = ((float)cc.w + 0.5f) * 0.16f + 0.0f;
  const float cy = ((float)cc.z + 0.5f) * 0.16f - 39.68f;
  f[0] = v.x; f[1] = v.y; f[2] = v.z; f[3] = v.w;
  f[4] = v.x - cx; f[5] = v.y - cy; f[6] = cx; f[7] = cy; f[8] = zc;
  const float msk = (m < np) ? 1.0f : 0.0f;
#pragma unroll
  for (int i = 0; i < 9; ++i) f[i] *= msk;
}

// ------------------------------------------------- K1: f-moments (layer-1 stats)

__global__ __launch_bounds__(256) void k_moments(
    const float4* __restrict__ vox, const int4* __restrict__ coords,
    const int* __restrict__ npnts, float* __restrict__ P1) {
  const int t = blockIdx.x * 256 + threadIdx.x;
  float acc[54];
#pragma unroll
  for (int v = 0; v < 54; ++v) acc[v] = 0.0f;

#pragma unroll
  for (int j = 0; j < K1_ITERS; ++j) {
    const int pt = t + j * K1_STRIDE;
    const int pil = pt >> 5;
    const int m = pt & 31;
    const float4 v = vox[pt];
    const int4 cc = coords[pil];
    const int np = npnts[pil];
    float z = v.z;
#pragma unroll
    for (int s = 1; s < 32; s <<= 1) z += __shfl_xor(z, s, 32);
    const float zc = z * (1.0f / 32.0f);
    float f[9];
    make_f(v, cc, np, m, zc, f);
    int vi = 0;
#pragma unroll
    for (int i = 0; i < 9; ++i) acc[vi++] += f[i];
#pragma unroll
    for (int i = 0; i < 9; ++i)
#pragma unroll
      for (int jj = i; jj < 9; ++jj) acc[vi++] += f[i] * f[jj];
  }

#pragma unroll
  for (int v = 0; v < 54; ++v) {
    float x = acc[v];
#pragma unroll
    for (int s = 1; s < 64; s <<= 1) x += __shfl_xor(x, s, 64);
    acc[v] = x;
  }
  __shared__ float red[4][54];
  const int wave = threadIdx.x >> 6, lane = threadIdx.x & 63;
  if (lane == 0) {
#pragma unroll
    for (int v = 0; v < 54; ++v) red[wave][v] = acc[v];
  }
  __syncthreads();
  if (threadIdx.x < 54) {
    float s = red[0][threadIdx.x] + red[1][threadIdx.x] + red[2][threadIdx.x] + red[3][threadIdx.x];
    P1[threadIdx.x * K1_BLOCKS + blockIdx.x] = s;
  }
}

// ------------------------------------------------- generic row reduce (f32 -> f64)

__global__ __launch_bounds__(256) void k_rowreduce(
    const float* __restrict__ src, double* __restrict__ dst, int ncols) {
  const int row = blockIdx.x;
  const float* p = src + row * ncols;
  double sd = 0.0;
  for (int i = threadIdx.x; i < ncols; i += 256) sd += (double)p[i];
#pragma unroll
  for (int s = 1; s < 64; s <<= 1) sd += __shfl_xor(sd, s, 64);
  __shared__ double rd[4];
  const int wave = threadIdx.x >> 6, lane = threadIdx.x & 63;
  if (lane == 0) rd[wave] = sd;
  __syncthreads();
  if (threadIdx.x == 0) dst[row] = rd[0] + rd[1] + rd[2] + rd[3];
}

// ------------------------------------------------- finalize layer-1 BN params

__global__ void k_fin1(const double* __restrict__ T1, const float* __restrict__ W1,
                       const float* __restrict__ g1, const float* __restrict__ b1,
                       float* __restrict__ params) {
  const int c = threadIdx.x;  // 64
  double w[9];
#pragma unroll
  for (int i = 0; i < 9; ++i) w[i] = (double)W1[i * 64 + c];
  double mean = 0.0;
#pragma unroll
  for (int i = 0; i < 9; ++i) mean += w[i] * T1[i];
  mean /= (double)NPTS;
  double e2 = 0.0;
  int v = 9;
#pragma unroll
  for (int i = 0; i < 9; ++i)
#pragma unroll
    for (int j = i; j < 9; ++j) {
      const double t = T1[v++] * w[i] * w[j];
      e2 += (i == j) ? t : 2.0 * t;
    }
  e2 /= (double)NPTS;
  const double var = e2 - mean * mean;
  const double a = (double)g1[c] / sqrt(var + 0.001);
  params[c] = (float)a;
  params[64 + c] = (float)((double)b1[c] - mean * a);
}

// ------------------------------------------------- K3: layer-2 stats
// Phase A: 2 threads/point compute h1 -> LDS. Phase B: lane=channel, thread
// walks one pillar; broadcast b128 LDS reads vs register-resident W2 column.

__global__ __launch_bounds__(256, 4) void k_stats2(
    const float4* __restrict__ vox, const int4* __restrict__ coords,
    const int* __restrict__ npnts, const float* __restrict__ W1,
    const float* __restrict__ W2, const float* __restrict__ params,
    float* __restrict__ P2) {
  __shared__ __align__(16) float W1t[9 * 64];           // same layout as W1: [i][c]
  __shared__ __align__(16) float a1s[64], b1s[64];
  __shared__ __align__(16) float h1s[CHUNK * LDH];      // 34816 B
  __shared__ float redS[4][64], redQ[4][64];

  const int t = threadIdx.x;
  for (int i = t; i < 576; i += 256) W1t[i] = W1[i];
  if (t < 64) { a1s[t] = params[t]; b1s[t] = params[64 + t]; }

  const int c = t & 63;           // phase-B channel
  float w2[64];
#pragma unroll
  for (int k = 0; k < 64; ++k) w2[k] = W2[k * 64 + c];
  __syncthreads();

  const int p_loc = t >> 1;             // 0..127
  const int ch_half = (t & 1) * 32;     // phase-A channel half
  const int g = t >> 6;                 // phase-B pillar-in-batch (= wave)
  float psum = 0.0f, psq = 0.0f;

  for (int bb = blockIdx.x; bb < NBATCH; bb += SB) {
    // ---- phase A: h1 for 128 points
    const int pt = bb * CHUNK + p_loc;
    const float4 v = vox[pt];
    const int4 cc = coords[pt >> 5];
    const int np = npnts[pt >> 5];
    float z = v.z;
#pragma unroll
    for (int s = 1; s < 64; s <<= 1) z += __shfl_xor(z, s, 64);  // 32 pts x2 lanes
    const float zc = z * (1.0f / 64.0f);
    float f[9];
    make_f(v, cc, np, pt & 31, zc, f);
    float* row = &h1s[p_loc * LDH];
#pragma unroll
    for (int j = 0; j < 8; ++j) {
      const int c0 = ch_half + 4 * j;
      float y0 = 0, y1 = 0, y2 = 0, y3 = 0;
#pragma unroll
      for (int i = 0; i < 9; ++i) {
        const float4 w = *(const float4*)&W1t[i * 64 + c0];
        y0 = fmaf(f[i], w.x, y0);
        y1 = fmaf(f[i], w.y, y1);
        y2 = fmaf(f[i], w.z, y2);
        y3 = fmaf(f[i], w.w, y3);
      }
      const float4 a = *(const float4*)&a1s[c0];
      const float4 b = *(const float4*)&b1s[c0];
      float4 h;
      h.x = fmaxf(fmaf(y0, a.x, b.x), 0.0f);
      h.y = fmaxf(fmaf(y1, a.y, b.y), 0.0f);
      h.z = fmaxf(fmaf(y2, a.z, b.z), 0.0f);
      h.w = fmaxf(fmaf(y3, a.w, b.w), 0.0f);
      *(float4*)&row[c0] = h;
    }
    __syncthreads();
    // ---- phase B: y2 for (channel c, pillar g), accumulate stats in-thread
#pragma unroll 2
    for (int pp = 0; pp < 32; ++pp) {
      const float4* hr = (const float4*)&h1s[(g * 32 + pp) * LDH];
      float y0 = 0, y1 = 0, y2 = 0, y3 = 0;
#pragma unroll
      for (int a4 = 0; a4 < 16; ++a4) {
        const float4 hv = hr[a4];   // broadcast: all lanes same address
        y0 = fmaf(hv.x, w2[4 * a4 + 0], y0);
        y1 = fmaf(hv.y, w2[4 * a4 + 1], y1);
        y2 = fmaf(hv.z, w2[4 * a4 + 2], y2);
        y3 = fmaf(hv.w, w2[4 * a4 + 3], y3);
      }
      const float y = (y0 + y1) + (y2 + y3);
      psum += y;
      psq = fmaf(y, y, psq);
    }
    __syncthreads();
  }

  const int wave = t >> 6;
  redS[wave][c] = psum;
  redQ[wave][c] = psq;
  __syncthreads();
  if (t < 64) {
    const float s = redS[0][t] + redS[1][t] + redS[2][t] + redS[3][t];
    const float q = redQ[0][t] + redQ[1][t] + redQ[2][t] + redQ[3][t];
    P2[t * SB + blockIdx.x] = s;
    P2[(64 + t) * SB + blockIdx.x] = q;
  }
}

// ------------------------------------------------- finalize layer-2 BN params

__global__ void k_fin2(const double* __restrict__ T2, const float* __restrict__ g2,
                       const float* __restrict__ b2, float* __restrict__ params) {
  const int c = threadIdx.x;  // 64
  const double mean = T2[c] / (double)NPTS;
  const double var = T2[64 + c] / (double)NPTS - mean * mean;
  const double a = (double)g2[c] / sqrt(var + 0.001);
  params[128 + c] = (float)a;
  params[192 + c] = (float)((double)b2[c] - mean * a);
}

// ------------------------------------------------- K5: output pass

__global__ __launch_bounds__(256, 4) void k_out(
    const float4* __restrict__ vox, const int4* __restrict__ coords,
    const int* __restrict__ npnts, const float* __restrict__ W1,
    const float* __restrict__ W2, const float* __restrict__ params,
    float* __restrict__ out) {
  __shared__ __align__(16) float W1t[9 * 64];
  __shared__ __align__(16) float a1s[64], b1s[64];
  __shared__ __align__(16) float h1s[CHUNK * LDH];

  const int t = threadIdx.x;
  for (int i = t; i < 576; i += 256) W1t[i] = W1[i];
  if (t < 64) { a1s[t] = params[t]; b1s[t] = params[64 + t]; }

  const int c = t & 63;
  float w2[64];
#pragma unroll
  for (int k = 0; k < 64; ++k) w2[k] = W2[k * 64 + c];
  const float a2 = params[128 + c];
  const float b2 = params[192 + c];
  __syncthreads();

  const int p_loc = t >> 1;
  const int ch_half = (t & 1) * 32;
  const int g = t >> 6;

  for (int bb = blockIdx.x; bb < NBATCH; bb += SB) {
    const int pt = bb * CHUNK + p_loc;
    const float4 v = vox[pt];
    const int4 cc = coords[pt >> 5];
    const int np = npnts[pt >> 5];
    float z = v.z;
#pragma unroll
    for (int s = 1; s < 64; s <<= 1) z += __shfl_xor(z, s, 64);
    const float zc = z * (1.0f / 64.0f);
    float f[9];
    make_f(v, cc, np, pt & 31, zc, f);
    float* row = &h1s[p_loc * LDH];
#pragma unroll
    for (int j = 0; j < 8; ++j) {
      const int c0 = ch_half + 4 * j;
      float y0 = 0, y1 = 0, y2 = 0, y3 = 0;
#pragma unroll
      for (int i = 0; i < 9; ++i) {
        const float4 w = *(const float4*)&W1t[i * 64 + c0];
        y0 = fmaf(f[i], w.x, y0);
        y1 = fmaf(f[i], w.y, y1);
        y2 = fmaf(f[i], w.z, y2);
        y3 = fmaf(f[i], w.w, y3);
      }
      const float4 a = *(const float4*)&a1s[c0];
      const float4 b = *(const float4*)&b1s[c0];
      float4 h;
      h.x = fmaxf(fmaf(y0, a.x, b.x), 0.0f);
      h.y = fmaxf(fmaf(y1, a.y, b.y), 0.0f);
      h.z = fmaxf(fmaf(y2, a.z, b.z), 0.0f);
      h.w = fmaxf(fmaf(y3, a.w, b.w), 0.0f);
      *(float4*)&row[c0] = h;
    }
    __syncthreads();
    // phase B: channel c, pillar g; max over 32 points in-thread (h2 >= 0)
    float mx = 0.0f;
#pragma unroll 2
    for (int pp = 0; pp < 32; ++pp) {
      const float4* hr = (const float4*)&h1s[(g * 32 + pp) * LDH];
      float y0 = 0, y1 = 0, y2 = 0, y3 = 0;
#pragma unroll
      for (int a4 = 0; a4 < 16; ++a4) {
        const float4 hv = hr[a4];
        y0 = fmaf(hv.x, w2[4 * a4 + 0], y0);
        y1 = fmaf(hv.y, w2[4 * a4 + 1], y1);
        y2 = fmaf(hv.z, w2[4 * a4 + 2], y2);
        y3 = fmaf(hv.w, w2[4 * a4 + 3], y3);
      }
      const float y = (y0 + y1) + (y2 + y3);
      mx = fmaxf(mx, fmaxf(fmaf(y, a2, b2), 0.0f));
    }
    out[(bb * 4 + g) * 64 + c] = mx;
    __syncthreads();
  }
}

// ---------------------------------------------------------------- launch

extern "C" void kernel_launch(void* const* d_in, const int* in_sizes, int n_in,
                              void* d_out, int out_size, void* d_ws, size_t ws_size,
                              hipStream_t stream) {
  const float4* vox = (const float4*)d_in[0];
  const int4* coords = (const int4*)d_in[1];
  const int* npnts = (const int*)d_in[2];
  const float* W1 = (const float*)d_in[3];
  const float* g1 = (const float*)d_in[4];
  const float* b1 = (const float*)d_in[5];
  const float* W2 = (const float*)d_in[6];
  const float* g2 = (const float*)d_in[7];
  const float* b2 = (const float*)d_in[8];
  float* out = (float*)d_out;

  char* w = (char*)d_ws;
  double* T1 = (double*)w;                                   // 54 doubles
  double* T2 = (double*)(w + 512);                           // 128 doubles
  float* P1 = (float*)(w + 1536);                            // 54*1500 f32
  float* P2 = (float*)(w + 1536 + 54 * K1_BLOCKS * 4);       // 128*SB f32
  float* params = (float*)(w + 1536 + 54 * K1_BLOCKS * 4 + 128 * SB * 4);  // 256 f32

  k_moments<<<K1_BLOCKS, 256, 0, stream>>>(vox, coords, npnts, P1);
  k_rowreduce<<<54, 256, 0, stream>>>(P1, T1, K1_BLOCKS);
  k_fin1<<<1, 64, 0, stream>>>(T1, W1, g1, b1, params);
  k_stats2<<<SB, 256, 0, stream>>>(vox, coords, npnts, W1, W2, params, P2);
  k_rowreduce<<<128, 256, 0, stream>>>(P2, T2, SB);
  k_fin2<<<1, 64, 0, stream>>>(T2, g2, b2, params);
  k_out<<<SB, 256, 0, stream>>>(vox, coords, npnts, W1, W2, params, out);
}

// Round 3
// 689.894 us; speedup vs baseline: 3.5913x; 2.9809x over previous
//
#include <hip/hip_runtime.h>
#include <math.h>

#define NB 4
#define NPI 12000
#define NM 32
#define NPTS (NB*NPI*NM)      // 1536000
#define NPIL (NB*NPI)         // 48000

// k_moments config
#define K1_BLOCKS 1500
#define K1_STRIDE (K1_BLOCKS*256)   // 384000
#define K1_ITERS 4                  // NPTS / K1_STRIDE

// heavy-kernel config: 128 points (4 pillars) per batch
#define CHUNK 128
#define NBATCH (NPTS/CHUNK)   // 12000
#define SB 1024               // grid for k_stats2 / k_out
#define LDH 68                // padded h1 row stride (floats); 68*4B=272B, 16B-aligned rows

// ---------------------------------------------------------------- helpers

__device__ __forceinline__ void make_f(float4 v, int4 cc, int np, int m, float zc, float f[9]) {
  const float cx = ((float)cc.w + 0.5f) * 0.16f + 0.0f;
  const float cy = ((float)cc.z + 0.5f) * 0.16f - 39.68f;
  f[0] = v.x; f[1] = v.y; f[2] = v.z; f[3] = v.w;
  f[4] = v.x - cx; f[5] = v.y - cy; f[6] = cx; f[7] = cy; f[8] = zc;
  const float msk = (m < np) ? 1.0f : 0.0f;
#pragma unroll
  for (int i = 0; i < 9; ++i) f[i] *= msk;
}

// ------------------------------------------------- K1: f-moments (layer-1 stats)

__global__ __launch_bounds__(256) void k_moments(
    const float4* __restrict__ vox, const int4* __restrict__ coords,
    const int* __restrict__ npnts, float* __restrict__ P1) {
  const int t = blockIdx.x * 256 + threadIdx.x;
  float acc[54];
#pragma unroll
  for (int v = 0; v < 54; ++v) acc[v] = 0.0f;

#pragma unroll
  for (int j = 0; j < K1_ITERS; ++j) {
    const int pt = t + j * K1_STRIDE;
    const int pil = pt >> 5;
    const int m = pt & 31;
    const float4 v = vox[pt];
    const int4 cc = coords[pil];
    const int np = npnts[pil];
    float z = v.z;
#pragma unroll
    for (int s = 1; s < 32; s <<= 1) z += __shfl_xor(z, s, 32);
    const float zc = z * (1.0f / 32.0f);
    float f[9];
    make_f(v, cc, np, m, zc, f);
    int vi = 0;
#pragma unroll
    for (int i = 0; i < 9; ++i) acc[vi++] += f[i];
#pragma unroll
    for (int i = 0; i < 9; ++i)
#pragma unroll
      for (int jj = i; jj < 9; ++jj) acc[vi++] += f[i] * f[jj];
  }

#pragma unroll
  for (int v = 0; v < 54; ++v) {
    float x = acc[v];
#pragma unroll
    for (int s = 1; s < 64; s <<= 1) x += __shfl_xor(x, s, 64);
    acc[v] = x;
  }
  __shared__ float red[4][54];
  const int wave = threadIdx.x >> 6, lane = threadIdx.x & 63;
  if (lane == 0) {
#pragma unroll
    for (int v = 0; v < 54; ++v) red[wave][v] = acc[v];
  }
  __syncthreads();
  if (threadIdx.x < 54) {
    float s = red[0][threadIdx.x] + red[1][threadIdx.x] + red[2][threadIdx.x] + red[3][threadIdx.x];
    P1[threadIdx.x * K1_BLOCKS + blockIdx.x] = s;
  }
}

// ------------------------------------------------- generic row reduce (f32 -> f64)

__global__ __launch_bounds__(256) void k_rowreduce(
    const float* __restrict__ src, double* __restrict__ dst, int ncols) {
  const int row = blockIdx.x;
  const float* p = src + row * ncols;
  double sd = 0.0;
  for (int i = threadIdx.x; i < ncols; i += 256) sd += (double)p[i];
#pragma unroll
  for (int s = 1; s < 64; s <<= 1) sd += __shfl_xor(sd, s, 64);
  __shared__ double rd[4];
  const int wave = threadIdx.x >> 6, lane = threadIdx.x & 63;
  if (lane == 0) rd[wave] = sd;
  __syncthreads();
  if (threadIdx.x == 0) dst[row] = rd[0] + rd[1] + rd[2] + rd[3];
}

// ------------------------------------------------- finalize layer-1 BN params

__global__ void k_fin1(const double* __restrict__ T1, const float* __restrict__ W1,
                       const float* __restrict__ g1, const float* __restrict__ b1,
                       float* __restrict__ params) {
  const int c = threadIdx.x;  // 64
  double w[9];
#pragma unroll
  for (int i = 0; i < 9; ++i) w[i] = (double)W1[i * 64 + c];
  double mean = 0.0;
#pragma unroll
  for (int i = 0; i < 9; ++i) mean += w[i] * T1[i];
  mean /= (double)NPTS;
  double e2 = 0.0;
  int v = 9;
#pragma unroll
  for (int i = 0; i < 9; ++i)
#pragma unroll
    for (int j = i; j < 9; ++j) {
      const double t = T1[v++] * w[i] * w[j];
      e2 += (i == j) ? t : 2.0 * t;
    }
  e2 /= (double)NPTS;
  const double var = e2 - mean * mean;
  const double a = (double)g1[c] / sqrt(var + 0.001);
  params[c] = (float)a;
  params[64 + c] = (float)((double)b1[c] - mean * a);
}

// ------------------------------------------------- K3: layer-2 stats
// Phase A: 2 threads/point compute h1 -> LDS. Phase B: lane=channel, thread
// walks one pillar; broadcast b128 LDS reads vs register-resident W2 column.

__global__ __launch_bounds__(256, 4) void k_stats2(
    const float4* __restrict__ vox, const int4* __restrict__ coords,
    const int* __restrict__ npnts, const float* __restrict__ W1,
    const float* __restrict__ W2, const float* __restrict__ params,
    float* __restrict__ P2) {
  __shared__ __align__(16) float W1t[9 * 64];           // same layout as W1: [i][c]
  __shared__ __align__(16) float a1s[64], b1s[64];
  __shared__ __align__(16) float h1s[CHUNK * LDH];      // 34816 B
  __shared__ float redS[4][64], redQ[4][64];

  const int t = threadIdx.x;
  for (int i = t; i < 576; i += 256) W1t[i] = W1[i];
  if (t < 64) { a1s[t] = params[t]; b1s[t] = params[64 + t]; }

  const int c = t & 63;           // phase-B channel
  float w2[64];
#pragma unroll
  for (int k = 0; k < 64; ++k) w2[k] = W2[k * 64 + c];
  __syncthreads();

  const int p_loc = t >> 1;             // 0..127
  const int ch_half = (t & 1) * 32;     // phase-A channel half
  const int g = t >> 6;                 // phase-B pillar-in-batch (= wave)
  float psum = 0.0f, psq = 0.0f;

  for (int bb = blockIdx.x; bb < NBATCH; bb += SB) {
    // ---- phase A: h1 for 128 points
    const int pt = bb * CHUNK + p_loc;
    const float4 v = vox[pt];
    const int4 cc = coords[pt >> 5];
    const int np = npnts[pt >> 5];
    float z = v.z;
#pragma unroll
    for (int s = 1; s < 64; s <<= 1) z += __shfl_xor(z, s, 64);  // 32 pts x2 lanes
    const float zc = z * (1.0f / 64.0f);
    float f[9];
    make_f(v, cc, np, pt & 31, zc, f);
    float* row = &h1s[p_loc * LDH];
#pragma unroll
    for (int j = 0; j < 8; ++j) {
      const int c0 = ch_half + 4 * j;
      float y0 = 0, y1 = 0, y2 = 0, y3 = 0;
#pragma unroll
      for (int i = 0; i < 9; ++i) {
        const float4 w = *(const float4*)&W1t[i * 64 + c0];
        y0 = fmaf(f[i], w.x, y0);
        y1 = fmaf(f[i], w.y, y1);
        y2 = fmaf(f[i], w.z, y2);
        y3 = fmaf(f[i], w.w, y3);
      }
      const float4 a = *(const float4*)&a1s[c0];
      const float4 b = *(const float4*)&b1s[c0];
      float4 h;
      h.x = fmaxf(fmaf(y0, a.x, b.x), 0.0f);
      h.y = fmaxf(fmaf(y1, a.y, b.y), 0.0f);
      h.z = fmaxf(fmaf(y2, a.z, b.z), 0.0f);
      h.w = fmaxf(fmaf(y3, a.w, b.w), 0.0f);
      *(float4*)&row[c0] = h;
    }
    __syncthreads();
    // ---- phase B: y2 for (channel c, pillar g), accumulate stats in-thread
#pragma unroll 2
    for (int pp = 0; pp < 32; ++pp) {
      const float4* hr = (const float4*)&h1s[(g * 32 + pp) * LDH];
      float y0 = 0, y1 = 0, y2 = 0, y3 = 0;
#pragma unroll
      for (int a4 = 0; a4 < 16; ++a4) {
        const float4 hv = hr[a4];   // broadcast: all lanes same address
        y0 = fmaf(hv.x, w2[4 * a4 + 0], y0);
        y1 = fmaf(hv.y, w2[4 * a4 + 1], y1);
        y2 = fmaf(hv.z, w2[4 * a4 + 2], y2);
        y3 = fmaf(hv.w, w2[4 * a4 + 3], y3);
      }
      const float y = (y0 + y1) + (y2 + y3);
      psum += y;
      psq = fmaf(y, y, psq);
    }
    __syncthreads();
  }

  const int wave = t >> 6;
  redS[wave][c] = psum;
  redQ[wave][c] = psq;
  __syncthreads();
  if (t < 64) {
    const float s = redS[0][t] + redS[1][t] + redS[2][t] + redS[3][t];
    const float q = redQ[0][t] + redQ[1][t] + redQ[2][t] + redQ[3][t];
    P2[t * SB + blockIdx.x] = s;
    P2[(64 + t) * SB + blockIdx.x] = q;
  }
}

// ------------------------------------------------- finalize layer-2 BN params

__global__ void k_fin2(const double* __restrict__ T2, const float* __restrict__ g2,
                       const float* __restrict__ b2, float* __restrict__ params) {
  const int c = threadIdx.x;  // 64
  const double mean = T2[c] / (double)NPTS;
  const double var = T2[64 + c] / (double)NPTS - mean * mean;
  const double a = (double)g2[c] / sqrt(var + 0.001);
  params[128 + c] = (float)a;
  params[192 + c] = (float)((double)b2[c] - mean * a);
}

// ------------------------------------------------- K5: output pass
// __launch_bounds__(256,2): round-2 ran (256,4) -> allocator fell to 64 VGPR
// and spilled w2[64] to scratch (FETCH_SIZE 5.9 GB, 44% HBM). Cap 256 VGPRs.

__global__ __launch_bounds__(256, 2) void k_out(
    const float4* __restrict__ vox, const int4* __restrict__ coords,
    const int* __restrict__ npnts, const float* __restrict__ W1,
    const float* __restrict__ W2, const float* __restrict__ params,
    float* __restrict__ out) {
  __shared__ __align__(16) float W1t[9 * 64];
  __shared__ __align__(16) float a1s[64], b1s[64];
  __shared__ __align__(16) float h1s[CHUNK * LDH];

  const int t = threadIdx.x;
  for (int i = t; i < 576; i += 256) W1t[i] = W1[i];
  if (t < 64) { a1s[t] = params[t]; b1s[t] = params[64 + t]; }

  const int c = t & 63;
  float w2[64];
#pragma unroll
  for (int k = 0; k < 64; ++k) w2[k] = W2[k * 64 + c];
  const float a2 = params[128 + c];
  const float b2 = params[192 + c];
  __syncthreads();

  const int p_loc = t >> 1;
  const int ch_half = (t & 1) * 32;
  const int g = t >> 6;

  for (int bb = blockIdx.x; bb < NBATCH; bb += SB) {
    const int pt = bb * CHUNK + p_loc;
    const float4 v = vox[pt];
    const int4 cc = coords[pt >> 5];
    const int np = npnts[pt >> 5];
    float z = v.z;
#pragma unroll
    for (int s = 1; s < 64; s <<= 1) z += __shfl_xor(z, s, 64);
    const float zc = z * (1.0f / 64.0f);
    float f[9];
    make_f(v, cc, np, pt & 31, zc, f);
    float* row = &h1s[p_loc * LDH];
#pragma unroll
    for (int j = 0; j < 8; ++j) {
      const int c0 = ch_half + 4 * j;
      float y0 = 0, y1 = 0, y2 = 0, y3 = 0;
#pragma unroll
      for (int i = 0; i < 9; ++i) {
        const float4 w = *(const float4*)&W1t[i * 64 + c0];
        y0 = fmaf(f[i], w.x, y0);
        y1 = fmaf(f[i], w.y, y1);
        y2 = fmaf(f[i], w.z, y2);
        y3 = fmaf(f[i], w.w, y3);
      }
      const float4 a = *(const float4*)&a1s[c0];
      const float4 b = *(const float4*)&b1s[c0];
      float4 h;
      h.x = fmaxf(fmaf(y0, a.x, b.x), 0.0f);
      h.y = fmaxf(fmaf(y1, a.y, b.y), 0.0f);
      h.z = fmaxf(fmaf(y2, a.z, b.z), 0.0f);
      h.w = fmaxf(fmaf(y3, a.w, b.w), 0.0f);
      *(float4*)&row[c0] = h;
    }
    __syncthreads();
    // phase B: channel c, pillar g; max over 32 points in-thread (h2 >= 0)
    float mx = 0.0f;
#pragma unroll 2
    for (int pp = 0; pp < 32; ++pp) {
      const float4* hr = (const float4*)&h1s[(g * 32 + pp) * LDH];
      float y0 = 0, y1 = 0, y2 = 0, y3 = 0;
#pragma unroll
      for (int a4 = 0; a4 < 16; ++a4) {
        const float4 hv = hr[a4];
        y0 = fmaf(hv.x, w2[4 * a4 + 0], y0);
        y1 = fmaf(hv.y, w2[4 * a4 + 1], y1);
        y2 = fmaf(hv.z, w2[4 * a4 + 2], y2);
        y3 = fmaf(hv.w, w2[4 * a4 + 3], y3);
      }
      const float y = (y0 + y1) + (y2 + y3);
      mx = fmaxf(mx, fmaxf(fmaf(y, a2, b2), 0.0f));
    }
    out[(bb * 4 + g) * 64 + c] = mx;
    __syncthreads();
  }
}

// ---------------------------------------------------------------- launch

extern "C" void kernel_launch(void* const* d_in, const int* in_sizes, int n_in,
                              void* d_out, int out_size, void* d_ws, size_t ws_size,
                              hipStream_t stream) {
  const float4* vox = (const float4*)d_in[0];
  const int4* coords = (const int4*)d_in[1];
  const int* npnts = (const int*)d_in[2];
  const float* W1 = (const float*)d_in[3];
  const float* g1 = (const float*)d_in[4];
  const float* b1 = (const float*)d_in[5];
  const float* W2 = (const float*)d_in[6];
  const float* g2 = (const float*)d_in[7];
  const float* b2 = (const float*)d_in[8];
  float* out = (float*)d_out;

  char* w = (char*)d_ws;
  double* T1 = (double*)w;                                   // 54 doubles
  double* T2 = (double*)(w + 512);                           // 128 doubles
  float* P1 = (float*)(w + 1536);                            // 54*1500 f32
  float* P2 = (float*)(w + 1536 + 54 * K1_BLOCKS * 4);       // 128*SB f32
  float* params = (float*)(w + 1536 + 54 * K1_BLOCKS * 4 + 128 * SB * 4);  // 256 f32

  k_moments<<<K1_BLOCKS, 256, 0, stream>>>(vox, coords, npnts, P1);
  k_rowreduce<<<54, 256, 0, stream>>>(P1, T1, K1_BLOCKS);
  k_fin1<<<1, 64, 0, stream>>>(T1, W1, g1, b1, params);
  k_stats2<<<SB, 256, 0, stream>>>(vox, coords, npnts, W1, W2, params, P2);
  k_rowreduce<<<128, 256, 0, stream>>>(P2, T2, SB);
  k_fin2<<<1, 64, 0, stream>>>(T2, g2, b2, params);
  k_out<<<SB, 256, 0, stream>>>(vox, coords, npnts, W1, W2, params, out);
}

// Round 4
// 623.878 us; speedup vs baseline: 3.9713x; 1.1058x over previous
//
#include <hip/hip_runtime.h>
#include <math.h>

#define NB 4
#define NPI 12000
#define NM 32
#define NPTS (NB*NPI*NM)      // 1536000
#define NPIL (NB*NPI)         // 48000

// k_moments config
#define K1_BLOCKS 1500
#define K1_STRIDE (K1_BLOCKS*256)   // 384000
#define K1_ITERS 4                  // NPTS / K1_STRIDE
#define NMOM 55                     // 9 Sf + 45 Sff + 1 valid-count

// heavy-kernel config: 128 points (4 pillars) per batch
#define CHUNK 128
#define NBATCH (NPTS/CHUNK)   // 12000
#define SB 1024               // grid for k_stats2 / k_out
#define LDH 68                // padded h1 row stride (floats)

// ---------------------------------------------------------------- helpers

__device__ __forceinline__ void make_f(float4 v, int4 cc, int np, int m, float zc, float f[9]) {
  const float cx = ((float)cc.w + 0.5f) * 0.16f + 0.0f;
  const float cy = ((float)cc.z + 0.5f) * 0.16f - 39.68f;
  f[0] = v.x; f[1] = v.y; f[2] = v.z; f[3] = v.w;
  f[4] = v.x - cx; f[5] = v.y - cy; f[6] = cx; f[7] = cy; f[8] = zc;
  const float msk = (m < np) ? 1.0f : 0.0f;
#pragma unroll
  for (int i = 0; i < 9; ++i) f[i] *= msk;
}

// ------------------------------------------------- K1: f-moments + valid count

__global__ __launch_bounds__(256) void k_moments(
    const float4* __restrict__ vox, const int4* __restrict__ coords,
    const int* __restrict__ npnts, float* __restrict__ P1) {
  const int t = blockIdx.x * 256 + threadIdx.x;
  float acc[NMOM];
#pragma unroll
  for (int v = 0; v < NMOM; ++v) acc[v] = 0.0f;

#pragma unroll
  for (int j = 0; j < K1_ITERS; ++j) {
    const int pt = t + j * K1_STRIDE;
    const int pil = pt >> 5;
    const int m = pt & 31;
    const float4 v = vox[pt];
    const int4 cc = coords[pil];
    const int np = npnts[pil];
    float z = v.z;
#pragma unroll
    for (int s = 1; s < 32; s <<= 1) z += __shfl_xor(z, s, 32);
    const float zc = z * (1.0f / 32.0f);
    float f[9];
    make_f(v, cc, np, m, zc, f);
    int vi = 0;
#pragma unroll
    for (int i = 0; i < 9; ++i) acc[vi++] += f[i];
#pragma unroll
    for (int i = 0; i < 9; ++i)
#pragma unroll
      for (int jj = i; jj < 9; ++jj) acc[vi++] += f[i] * f[jj];
    acc[54] += (m < np) ? 1.0f : 0.0f;
  }

#pragma unroll
  for (int v = 0; v < NMOM; ++v) {
    float x = acc[v];
#pragma unroll
    for (int s = 1; s < 64; s <<= 1) x += __shfl_xor(x, s, 64);
    acc[v] = x;
  }
  __shared__ float red[4][NMOM];
  const int wave = threadIdx.x >> 6, lane = threadIdx.x & 63;
  if (lane == 0) {
#pragma unroll
    for (int v = 0; v < NMOM; ++v) red[wave][v] = acc[v];
  }
  __syncthreads();
  if (threadIdx.x < NMOM) {
    float s = red[0][threadIdx.x] + red[1][threadIdx.x] + red[2][threadIdx.x] + red[3][threadIdx.x];
    P1[threadIdx.x * K1_BLOCKS + blockIdx.x] = s;
  }
}

// ------------------------------------------------- generic row reduce (f32 -> f64)

__global__ __launch_bounds__(256) void k_rowreduce(
    const float* __restrict__ src, double* __restrict__ dst, int ncols) {
  const int row = blockIdx.x;
  const float* p = src + row * ncols;
  double sd = 0.0;
  for (int i = threadIdx.x; i < ncols; i += 256) sd += (double)p[i];
#pragma unroll
  for (int s = 1; s < 64; s <<= 1) sd += __shfl_xor(sd, s, 64);
  __shared__ double rd[4];
  const int wave = threadIdx.x >> 6, lane = threadIdx.x & 63;
  if (lane == 0) rd[wave] = sd;
  __syncthreads();
  if (threadIdx.x == 0) dst[row] = rd[0] + rd[1] + rd[2] + rd[3];
}

// ------------------------------------------------- finalize layer-1 BN params

__global__ void k_fin1(const double* __restrict__ T1, const float* __restrict__ W1,
                       const float* __restrict__ g1, const float* __restrict__ b1,
                       float* __restrict__ params) {
  const int c = threadIdx.x;  // 64
  double w[9];
#pragma unroll
  for (int i = 0; i < 9; ++i) w[i] = (double)W1[i * 64 + c];
  double mean = 0.0;
#pragma unroll
  for (int i = 0; i < 9; ++i) mean += w[i] * T1[i];
  mean /= (double)NPTS;
  double e2 = 0.0;
  int v = 9;
#pragma unroll
  for (int i = 0; i < 9; ++i)
#pragma unroll
    for (int j = i; j < 9; ++j) {
      const double t = T1[v++] * w[i] * w[j];
      e2 += (i == j) ? t : 2.0 * t;
    }
  e2 /= (double)NPTS;
  const double var = e2 - mean * mean;
  const double a = (double)g1[c] / sqrt(var + 0.001);
  params[c] = (float)a;
  params[64 + c] = (float)((double)b1[c] - mean * a);
}

// ------------------------------------------------- K3: layer-2 stats (valid pts only)

__global__ __launch_bounds__(256, 4) void k_stats2(
    const float4* __restrict__ vox, const int4* __restrict__ coords,
    const int* __restrict__ npnts, const float* __restrict__ W1,
    const float* __restrict__ W2, const float* __restrict__ params,
    float* __restrict__ P2) {
  __shared__ __align__(16) float W1t[9 * 64];
  __shared__ __align__(16) float a1s[64], b1s[64];
  __shared__ __align__(16) float h1s[CHUNK * LDH];
  __shared__ float redS[4][64], redQ[4][64];

  const int t = threadIdx.x;
  for (int i = t; i < 576; i += 256) W1t[i] = W1[i];
  if (t < 64) { a1s[t] = params[t]; b1s[t] = params[64 + t]; }

  const int c = t & 63;
  float w2[64];
#pragma unroll
  for (int k = 0; k < 64; ++k) w2[k] = W2[k * 64 + c];
  __syncthreads();

  const int p_loc = t >> 1;
  const int ch_half = (t & 1) * 32;
  const int g = t >> 6;
  float psum = 0.0f, psq = 0.0f;

  for (int bb = blockIdx.x; bb < NBATCH; bb += SB) {
    // ---- phase A: h1 for 128 points
    const int pt = bb * CHUNK + p_loc;
    const float4 v = vox[pt];
    const int4 cc = coords[pt >> 5];
    const int np = npnts[pt >> 5];
    float z = v.z;
#pragma unroll
    for (int s = 1; s < 64; s <<= 1) z += __shfl_xor(z, s, 64);
    const float zc = z * (1.0f / 64.0f);
    float f[9];
    make_f(v, cc, np, pt & 31, zc, f);
    float* row = &h1s[p_loc * LDH];
#pragma unroll
    for (int j = 0; j < 8; ++j) {
      const int c0 = ch_half + 4 * j;
      float y0 = 0, y1 = 0, y2 = 0, y3 = 0;
#pragma unroll
      for (int i = 0; i < 9; ++i) {
        const float4 w = *(const float4*)&W1t[i * 64 + c0];
        y0 = fmaf(f[i], w.x, y0);
        y1 = fmaf(f[i], w.y, y1);
        y2 = fmaf(f[i], w.z, y2);
        y3 = fmaf(f[i], w.w, y3);
      }
      const float4 a = *(const float4*)&a1s[c0];
      const float4 b = *(const float4*)&b1s[c0];
      float4 h;
      h.x = fmaxf(fmaf(y0, a.x, b.x), 0.0f);
      h.y = fmaxf(fmaf(y1, a.y, b.y), 0.0f);
      h.z = fmaxf(fmaf(y2, a.z, b.z), 0.0f);
      h.w = fmaxf(fmaf(y3, a.w, b.w), 0.0f);
      *(float4*)&row[c0] = h;
    }
    __syncthreads();
    // ---- phase B: valid points only (np_g is wave-uniform -> no divergence).
    // Masked-point contributions are added analytically in k_fin2.
    const int np_g = npnts[bb * 4 + g];
#pragma unroll 2
    for (int pp = 0; pp < np_g; ++pp) {
      const float4* hr = (const float4*)&h1s[(g * 32 + pp) * LDH];
      float y0 = 0, y1 = 0, y2 = 0, y3 = 0;
#pragma unroll
      for (int a4 = 0; a4 < 16; ++a4) {
        const float4 hv = hr[a4];   // broadcast read
        y0 = fmaf(hv.x, w2[4 * a4 + 0], y0);
        y1 = fmaf(hv.y, w2[4 * a4 + 1], y1);
        y2 = fmaf(hv.z, w2[4 * a4 + 2], y2);
        y3 = fmaf(hv.w, w2[4 * a4 + 3], y3);
      }
      const float y = (y0 + y1) + (y2 + y3);
      psum += y;
      psq = fmaf(y, y, psq);
    }
    __syncthreads();
  }

  const int wave = t >> 6;
  redS[wave][c] = psum;
  redQ[wave][c] = psq;
  __syncthreads();
  if (t < 64) {
    const float s = redS[0][t] + redS[1][t] + redS[2][t] + redS[3][t];
    const float q = redQ[0][t] + redQ[1][t] + redQ[2][t] + redQ[3][t];
    P2[t * SB + blockIdx.x] = s;
    P2[(64 + t) * SB + blockIdx.x] = q;
  }
}

// ------------------------------------------------- finalize layer-2 BN params
// Adds the (NPTS - Nvalid) masked-point contributions in closed form, and
// precomputes the masked-point output vector h2_0 for k_out.

__global__ void k_fin2(const double* __restrict__ T2, const float* __restrict__ g2,
                       const float* __restrict__ b2, const float* __restrict__ W2,
                       const double* __restrict__ T1, float* __restrict__ params) {
  const int c = threadIdx.x;  // 64
  const double nmask = (double)NPTS - T1[54];
  double y20 = 0.0;
  for (int k = 0; k < 64; ++k) {
    const float h0 = fmaxf(params[64 + k], 0.0f);   // h1_0[k] = relu(b1adj[k])
    y20 += (double)h0 * (double)W2[k * 64 + c];
  }
  const double sum = T2[c] + nmask * y20;
  const double sq  = T2[64 + c] + nmask * y20 * y20;
  const double mean = sum / (double)NPTS;
  const double var = sq / (double)NPTS - mean * mean;
  const double a = (double)g2[c] / sqrt(var + 0.001);
  const double badj = (double)b2[c] - mean * a;
  params[128 + c] = (float)a;
  params[192 + c] = (float)badj;
  params[256 + c] = (float)fmax(a * y20 + badj, 0.0);   // h2_0[c] (relu)
}

// ------------------------------------------------- K5: output pass (valid pts only)

__global__ __launch_bounds__(256, 2) void k_out(
    const float4* __restrict__ vox, const int4* __restrict__ coords,
    const int* __restrict__ npnts, const float* __restrict__ W1,
    const float* __restrict__ W2, const float* __restrict__ params,
    float* __restrict__ out) {
  __shared__ __align__(16) float W1t[9 * 64];
  __shared__ __align__(16) float a1s[64], b1s[64];
  __shared__ __align__(16) float h1s[CHUNK * LDH];

  const int t = threadIdx.x;
  for (int i = t; i < 576; i += 256) W1t[i] = W1[i];
  if (t < 64) { a1s[t] = params[t]; b1s[t] = params[64 + t]; }

  const int c = t & 63;
  float w2[64];
#pragma unroll
  for (int k = 0; k < 64; ++k) w2[k] = W2[k * 64 + c];
  const float a2 = params[128 + c];
  const float b2 = params[192 + c];
  const float h20 = params[256 + c];
  __syncthreads();

  const int p_loc = t >> 1;
  const int ch_half = (t & 1) * 32;
  const int g = t >> 6;

  for (int bb = blockIdx.x; bb < NBATCH; bb += SB) {
    const int pt = bb * CHUNK + p_loc;
    const float4 v = vox[pt];
    const int4 cc = coords[pt >> 5];
    const int np = npnts[pt >> 5];
    float z = v.z;
#pragma unroll
    for (int s = 1; s < 64; s <<= 1) z += __shfl_xor(z, s, 64);
    const float zc = z * (1.0f / 64.0f);
    float f[9];
    make_f(v, cc, np, pt & 31, zc, f);
    float* row = &h1s[p_loc * LDH];
#pragma unroll
    for (int j = 0; j < 8; ++j) {
      const int c0 = ch_half + 4 * j;
      float y0 = 0, y1 = 0, y2 = 0, y3 = 0;
#pragma unroll
      for (int i = 0; i < 9; ++i) {
        const float4 w = *(const float4*)&W1t[i * 64 + c0];
        y0 = fmaf(f[i], w.x, y0);
        y1 = fmaf(f[i], w.y, y1);
        y2 = fmaf(f[i], w.z, y2);
        y3 = fmaf(f[i], w.w, y3);
      }
      const float4 a = *(const float4*)&a1s[c0];
      const float4 b = *(const float4*)&b1s[c0];
      float4 h;
      h.x = fmaxf(fmaf(y0, a.x, b.x), 0.0f);
      h.y = fmaxf(fmaf(y1, a.y, b.y), 0.0f);
      h.z = fmaxf(fmaf(y2, a.z, b.z), 0.0f);
      h.w = fmaxf(fmaf(y3, a.w, b.w), 0.0f);
      *(float4*)&row[c0] = h;
    }
    __syncthreads();
    // phase B: valid points only; masked points all produce h2_0 (folded below)
    const int np_g = npnts[bb * 4 + g];
    float mx = 0.0f;   // h2 = relu >= 0, so 0-init is exact
#pragma unroll 2
    for (int pp = 0; pp < np_g; ++pp) {
      const float4* hr = (const float4*)&h1s[(g * 32 + pp) * LDH];
      float y0 = 0, y1 = 0, y2 = 0, y3 = 0;
#pragma unroll
      for (int a4 = 0; a4 < 16; ++a4) {
        const float4 hv = hr[a4];
        y0 = fmaf(hv.x, w2[4 * a4 + 0], y0);
        y1 = fmaf(hv.y, w2[4 * a4 + 1], y1);
        y2 = fmaf(hv.z, w2[4 * a4 + 2], y2);
        y3 = fmaf(hv.w, w2[4 * a4 + 3], y3);
      }
      const float y = (y0 + y1) + (y2 + y3);
      mx = fmaxf(mx, fmaxf(fmaf(y, a2, b2), 0.0f));
    }
    if (np_g < 32) mx = fmaxf(mx, h20);
    out[(bb * 4 + g) * 64 + c] = mx;
    __syncthreads();
  }
}

// ---------------------------------------------------------------- launch

extern "C" void kernel_launch(void* const* d_in, const int* in_sizes, int n_in,
                              void* d_out, int out_size, void* d_ws, size_t ws_size,
                              hipStream_t stream) {
  const float4* vox = (const float4*)d_in[0];
  const int4* coords = (const int4*)d_in[1];
  const int* npnts = (const int*)d_in[2];
  const float* W1 = (const float*)d_in[3];
  const float* g1 = (const float*)d_in[4];
  const float* b1 = (const float*)d_in[5];
  const float* W2 = (const float*)d_in[6];
  const float* g2 = (const float*)d_in[7];
  const float* b2 = (const float*)d_in[8];
  float* out = (float*)d_out;

  char* w = (char*)d_ws;
  double* T1 = (double*)w;                                   // 55 doubles
  double* T2 = (double*)(w + 512);                           // 128 doubles
  float* P1 = (float*)(w + 1536);                            // 55*1500 f32
  float* P2 = (float*)(w + 1536 + NMOM * K1_BLOCKS * 4);     // 128*SB f32
  float* params = (float*)(w + 1536 + NMOM * K1_BLOCKS * 4 + 128 * SB * 4);  // 320 f32

  k_moments<<<K1_BLOCKS, 256, 0, stream>>>(vox, coords, npnts, P1);
  k_rowreduce<<<NMOM, 256, 0, stream>>>(P1, T1, K1_BLOCKS);
  k_fin1<<<1, 64, 0, stream>>>(T1, W1, g1, b1, params);
  k_stats2<<<SB, 256, 0, stream>>>(vox, coords, npnts, W1, W2, params, P2);
  k_rowreduce<<<128, 256, 0, stream>>>(P2, T2, SB);
  k_fin2<<<1, 64, 0, stream>>>(T2, g2, b2, W2, T1, params);
  k_out<<<SB, 256, 0, stream>>>(vox, coords, npnts, W1, W2, params, out);
}